// Round 13
// baseline (568.057 us; speedup 1.0000x reference)
//
#include <hip/hip_runtime.h>
#include <hip/hip_cooperative_groups.h>
#include <math.h>

namespace cg = cooperative_groups;

#define NEG_SLOPE 0.2f
__device__ __forceinline__ float leaky(float x) { return fmaxf(x, NEG_SLOPE * x); }

typedef _Float16 f16;
typedef _Float16 f16x4 __attribute__((ext_vector_type(4)));
typedef _Float16 f16x8 __attribute__((ext_vector_type(8)));
typedef float f32x4 __attribute__((ext_vector_type(4)));

__device__ __forceinline__ int kmap(int lh, int e) {
  return (e < 4) ? lh * 4 + e : 16 + lh * 4 + (e - 4);
}

#define W1_TOT (17 * 4 * 64 * 8)
#define W2_TOT (5 * 8 * 64 * 8)

// ---------------- cooperative CSR front-end: zero+packw | count+rank | partial | scan | offs ----------------
__global__ __launch_bounds__(256) void k_csr_build(
    const int* __restrict__ dst, int* __restrict__ deg, int* __restrict__ rank,
    int* __restrict__ part, int* __restrict__ offs, int n, int E, int nb,
    const float* __restrict__ W1, const float* __restrict__ as1f,
    const float* __restrict__ ad1f, const float* __restrict__ W2,
    const float* __restrict__ as2f, const float* __restrict__ ad2f,
    f16* __restrict__ Wp1, f16* __restrict__ Wp2) {
  cg::grid_group grid = cg::this_grid();
  __shared__ int s[256];
  __shared__ int ps[256];
  int nBlocks = gridDim.x;
  int gtid = blockIdx.x * 256 + threadIdx.x;
  int gstride = nBlocks * 256;

  // phase A: zero deg + weight pack (independent)
  for (int i = gtid; i < n; i += gstride) deg[i] = 0;
  for (int tid = gtid; tid < W1_TOT + W2_TOT; tid += gstride) {
    if (tid < W1_TOT) {
      int e = tid & 7, l = (tid >> 3) & 63, ks = (tid >> 9) & 3, nt = tid >> 11;
      int lh = l >> 4, li = l & 15;
      int k = ks * 32 + kmap(lh, e);
      float v;
      if (nt < 16) {
        v = W1[k * 256 + nt * 16 + li];
      } else {
        int h = li & 7;
        const float* a = (li < 8) ? (as1f + h * 32) : (ad1f + h * 32);
        v = 0.f;
        for (int j = 0; j < 32; ++j) v += W1[k * 256 + h * 32 + j] * a[j];
      }
      Wp1[tid] = (f16)v;
    } else {
      int t2 = tid - W1_TOT;
      int e = t2 & 7, l = (t2 >> 3) & 63, ks = (t2 >> 9) & 7, nt = t2 >> 12;
      int lh = l >> 4, li = l & 15;
      int k = ks * 32 + kmap(lh, e);
      float v = 0.f;
      if (nt < 4) {
        v = W2[k * 64 + nt * 16 + li];
      } else if (li == 0) {
        for (int j = 0; j < 64; ++j) v += W2[k * 64 + j] * as2f[j];
      } else if (li == 1) {
        for (int j = 0; j < 64; ++j) v += W2[k * 64 + j] * ad2f[j];
      }
      Wp2[t2] = (f16)v;
    }
  }
  grid.sync();

  // phase B: count + per-edge rank
  for (int e = gtid; e < E; e += gstride) {
    rank[e] = atomicAdd(&deg[dst[e]], 1);
  }
  grid.sync();

  // phase C1: per-256-chunk reductions
  for (int c = blockIdx.x; c < nb; c += nBlocks) {
    int i = c * 256 + threadIdx.x;
    s[threadIdx.x] = (i < n) ? deg[i] : 0;
    __syncthreads();
    for (int off = 128; off > 0; off >>= 1) {
      if (threadIdx.x < off) s[threadIdx.x] += s[threadIdx.x + off];
      __syncthreads();
    }
    if (threadIdx.x == 0) part[c] = s[0];
    __syncthreads();
  }
  grid.sync();

  // phase C2: block 0 exclusive-scans the partials (nb <= 256)
  if (blockIdx.x == 0) {
    int t = threadIdx.x;
    int v = (t < nb) ? part[t] : 0;
    ps[t] = v;
    __syncthreads();
    for (int off = 1; off < 256; off <<= 1) {
      int u = (t >= off) ? ps[t - off] : 0;
      __syncthreads();
      ps[t] += u;
      __syncthreads();
    }
    if (t < nb) part[t] = ps[t] - v;
  }
  grid.sync();

  // phase C3: per-chunk exclusive scan + base -> offs
  for (int c = blockIdx.x; c < nb; c += nBlocks) {
    int i = c * 256 + threadIdx.x;
    int v = (i < n) ? deg[i] : 0;
    s[threadIdx.x] = v;
    __syncthreads();
    for (int off = 1; off < 256; off <<= 1) {
      int u = (threadIdx.x >= off) ? s[threadIdx.x - off] : 0;
      __syncthreads();
      s[threadIdx.x] += u;
      __syncthreads();
    }
    int excl = part[c] + s[threadIdx.x] - v;
    if (i < n) offs[i] = excl;
    if (i == n - 1) offs[n] = excl + v;
    __syncthreads();
  }
}

// ---------------- fused: CSR fill (rank-based, no atomics) | MFMA GEMM1 ----------------
__global__ __launch_bounds__(256) void k_fill_gemm1(
    const int* __restrict__ src, const int* __restrict__ dst,
    const int* __restrict__ offs, const int* __restrict__ rank,
    int* __restrict__ col, int E, int fillBlocks,
    const float* __restrict__ x, const f16* __restrict__ Wp1,
    f16* __restrict__ h16, float* __restrict__ as, float* __restrict__ ad,
    int n, int nSlots) {
  if ((int)blockIdx.x < fillBlocks) {
    int e = blockIdx.x * 256 + threadIdx.x;
    if (e >= E) return;
    int d = dst[e];
    col[offs[d] + rank[e]] = src[e];
    return;
  }
  int slot = (blockIdx.x - fillBlocks) * 4 + (threadIdx.x >> 6);
  if (slot >= nSlots) return;
  int half = slot & 1;
  int wid = slot >> 1;
  int lane = threadIdx.x & 63, lh = lane >> 4, li = lane & 15;
  size_t arow = (size_t)min(wid * 16 + li, n - 1);
  f16x8 a[4];
#pragma unroll
  for (int ks = 0; ks < 4; ++ks) {
    float4 lo = *(const float4*)&x[arow * 128 + ks * 32 + lh * 4];
    float4 hi = *(const float4*)&x[arow * 128 + ks * 32 + 16 + lh * 4];
    a[ks][0] = (f16)lo.x; a[ks][1] = (f16)lo.y; a[ks][2] = (f16)lo.z; a[ks][3] = (f16)lo.w;
    a[ks][4] = (f16)hi.x; a[ks][5] = (f16)hi.y; a[ks][6] = (f16)hi.z; a[ks][7] = (f16)hi.w;
  }
  int rbase = wid * 16 + lh * 4;
  int ntBeg = half ? 8 : 0;
  int ntEnd = half ? 17 : 8;
  for (int nt = ntBeg; nt < ntEnd; ++nt) {
    f32x4 acc = {0.f, 0.f, 0.f, 0.f};
#pragma unroll
    for (int ks = 0; ks < 4; ++ks) {
      f16x8 b = *(const f16x8*)&Wp1[((nt * 4 + ks) * 64 + lane) * 8];
      acc = __builtin_amdgcn_mfma_f32_16x16x32_f16(a[ks], b, acc, 0, 0, 0);
    }
    if (nt < 16) {
#pragma unroll
      for (int r = 0; r < 4; ++r) {
        int rr = rbase + r;
        if (rr < n) h16[(size_t)rr * 256 + nt * 16 + li] = (f16)acc[r];
      }
    } else {
#pragma unroll
      for (int r = 0; r < 4; ++r) {
        int rr = rbase + r;
        if (rr < n) {
          if (li < 8) as[(size_t)rr * 8 + li] = acc[r];
          else        ad[(size_t)rr * 8 + (li - 8)] = acc[r];
        }
      }
    }
  }
}

// ---------------- fused: Layer-1 aggregation (16 nodes/block, static) + Layer-2 GEMM from LDS ----------------
#define RPAD 264
__global__ __launch_bounds__(256) void k_agg1_gemm2(const f16* __restrict__ h16,
    const float* __restrict__ as, const float* __restrict__ ad,
    const int* __restrict__ offs, const int* __restrict__ col,
    const float* __restrict__ b, const f16* __restrict__ Wp2,
    f16* __restrict__ h2, float* __restrict__ as2, float* __restrict__ ad2, int n) {
  __shared__ f16 rs[16][RPAD];
  int wave = threadIdx.x >> 6;
  int lane = threadIdx.x & 63;
  int head = lane >> 3;
  int c0 = lane * 4;

  // ---- phase 1: each wave aggregates 4 nodes ----
  for (int i = 0; i < 4; ++i) {
    int rl = wave * 4 + i;
    int node = blockIdx.x * 16 + rl;
    if (node >= n) {
      f16x4 z = {(f16)0.f, (f16)0.f, (f16)0.f, (f16)0.f};
      *(f16x4*)&rs[rl][c0] = z;
      continue;
    }
    node = __builtin_amdgcn_readfirstlane(node);
    int beg = offs[node], end = offs[node + 1];
    float adn = ad[node * 8 + head];

    float denom, ax, ay, az, aw;
    {  // self-loop
      float w = __expf(leaky(as[node * 8 + head] + adn));
      f16x4 g = *(const f16x4*)&h16[(size_t)node * 256 + c0];
      denom = w;
      ax = w * (float)g[0]; ay = w * (float)g[1];
      az = w * (float)g[2]; aw = w * (float)g[3];
    }
    int p = beg;
    for (; p + 8 <= end; p += 8) {
      int s[8];
#pragma unroll
      for (int j = 0; j < 8; ++j) s[j] = col[p + j];
      float e[8];
#pragma unroll
      for (int j = 0; j < 8; ++j) e[j] = as[s[j] * 8 + head];
      f16x4 g[8];
#pragma unroll
      for (int j = 0; j < 8; ++j) g[j] = *(const f16x4*)&h16[(size_t)s[j] * 256 + c0];
      float w[8];
#pragma unroll
      for (int j = 0; j < 8; ++j) w[j] = __expf(leaky(e[j] + adn));
#pragma unroll
      for (int j = 0; j < 8; ++j) {
        denom += w[j];
        ax += w[j] * (float)g[j][0]; ay += w[j] * (float)g[j][1];
        az += w[j] * (float)g[j][2]; aw += w[j] * (float)g[j][3];
      }
    }
    for (; p < end; ++p) {
      int s = col[p];
      float w = __expf(leaky(as[s * 8 + head] + adn));
      f16x4 g = *(const f16x4*)&h16[(size_t)s * 256 + c0];
      denom += w;
      ax += w * (float)g[0]; ay += w * (float)g[1];
      az += w * (float)g[2]; aw += w * (float)g[3];
    }
    float inv = 1.f / denom;
    float4 bv = *(const float4*)&b[c0];
    f16x4 o;
    o[0] = (f16)fmaxf(fmaf(ax, inv, bv.x), 0.f);
    o[1] = (f16)fmaxf(fmaf(ay, inv, bv.y), 0.f);
    o[2] = (f16)fmaxf(fmaf(az, inv, bv.z), 0.f);
    o[3] = (f16)fmaxf(fmaf(aw, inv, bv.w), 0.f);
    *(f16x4*)&rs[rl][c0] = o;
  }
  __syncthreads();

  // ---- phase 2: layer-2 GEMM for these 16 rows (A from LDS) ----
  int lh = lane >> 4, li = lane & 15;
  f16x8 a[8];
#pragma unroll
  for (int ks = 0; ks < 8; ++ks) {
    f16x4 lo = *(const f16x4*)&rs[li][ks * 32 + lh * 4];
    f16x4 hi = *(const f16x4*)&rs[li][ks * 32 + 16 + lh * 4];
    a[ks][0] = lo[0]; a[ks][1] = lo[1]; a[ks][2] = lo[2]; a[ks][3] = lo[3];
    a[ks][4] = hi[0]; a[ks][5] = hi[1]; a[ks][6] = hi[2]; a[ks][7] = hi[3];
  }
  int rbase = blockIdx.x * 16 + lh * 4;
  for (int nt = wave; nt < 5; nt += 4) {
    f32x4 acc = {0.f, 0.f, 0.f, 0.f};
#pragma unroll
    for (int ks = 0; ks < 8; ++ks) {
      f16x8 bb = *(const f16x8*)&Wp2[((nt * 8 + ks) * 64 + lane) * 8];
      acc = __builtin_amdgcn_mfma_f32_16x16x32_f16(a[ks], bb, acc, 0, 0, 0);
    }
    if (nt < 4) {
#pragma unroll
      for (int r = 0; r < 4; ++r) {
        int rr = rbase + r;
        if (rr < n) h2[(size_t)rr * 64 + nt * 16 + li] = (f16)acc[r];
      }
    } else {
#pragma unroll
      for (int r = 0; r < 4; ++r) {
        int rr = rbase + r;
        if (rr < n) {
          if (li == 0) as2[rr] = acc[r];
          else if (li == 1) ad2[rr] = acc[r];
        }
      }
    }
  }
}

// ---------------- Layer 2 aggregation: wave/node, 4 slots x 4 chains ----------------
__global__ __launch_bounds__(256) void k_agg2(const f16* __restrict__ h2,
    const float* __restrict__ as, const float* __restrict__ ad,
    const int* __restrict__ offs, const int* __restrict__ col,
    const float* __restrict__ b, float* __restrict__ out, int n) {
  int node = blockIdx.x * 4 + (threadIdx.x >> 6);
  if (node >= n) return;
  node = __builtin_amdgcn_readfirstlane(node);
  int lane = threadIdx.x & 63;
  int es = lane >> 4;
  int c = lane & 15;
  int beg = offs[node], end = offs[node + 1];
  int deg = end - beg;
  float adn = ad[node];

  float a0 = 0.f, a1 = 0.f, a2 = 0.f, a3 = 0.f, wsum = 0.f;
  if (es == 0) {
    float w = __expf(leaky(as[node] + adn));
    f16x4 g = *(const f16x4*)&h2[(size_t)node * 64 + c * 4];
    wsum = w;
    a0 = w * (float)g[0]; a1 = w * (float)g[1];
    a2 = w * (float)g[2]; a3 = w * (float)g[3];
  }
  for (int base = 0; base < deg; base += 16) {
    int s[4]; float e[4]; f16x4 g[4]; float w[4];
#pragma unroll
    for (int q = 0; q < 4; ++q) {
      int idx = base + q * 4 + es;
      s[q] = (idx < deg) ? col[beg + idx] : node;
    }
#pragma unroll
    for (int q = 0; q < 4; ++q) e[q] = as[s[q]];
#pragma unroll
    for (int q = 0; q < 4; ++q) g[q] = *(const f16x4*)&h2[(size_t)s[q] * 64 + c * 4];
#pragma unroll
    for (int q = 0; q < 4; ++q) {
      int idx = base + q * 4 + es;
      w[q] = (idx < deg) ? __expf(leaky(e[q] + adn)) : 0.f;
    }
#pragma unroll
    for (int q = 0; q < 4; ++q) {
      wsum += w[q];
      a0 += w[q] * (float)g[q][0]; a1 += w[q] * (float)g[q][1];
      a2 += w[q] * (float)g[q][2]; a3 += w[q] * (float)g[q][3];
    }
  }
  a0 += __shfl_xor(a0, 16, 64); a1 += __shfl_xor(a1, 16, 64);
  a2 += __shfl_xor(a2, 16, 64); a3 += __shfl_xor(a3, 16, 64);
  wsum += __shfl_xor(wsum, 16, 64);
  a0 += __shfl_xor(a0, 32, 64); a1 += __shfl_xor(a1, 32, 64);
  a2 += __shfl_xor(a2, 32, 64); a3 += __shfl_xor(a3, 32, 64);
  wsum += __shfl_xor(wsum, 32, 64);
  if (es == 0) {
    float inv = 1.f / wsum;
    float4 bv = *(const float4*)&b[c * 4];
    f32x4 o;
    o[0] = fmaxf(fmaf(a0, inv, bv.x), 0.f);
    o[1] = fmaxf(fmaf(a1, inv, bv.y), 0.f);
    o[2] = fmaxf(fmaf(a2, inv, bv.z), 0.f);
    o[3] = fmaxf(fmaf(a3, inv, bv.w), 0.f);
    __builtin_nontemporal_store(o, (f32x4*)&out[(size_t)node * 64 + c * 4]);
  }
}

extern "C" void kernel_launch(void* const* d_in, const int* in_sizes, int n_in,
                              void* d_out, int out_size, void* d_ws, size_t ws_size,
                              hipStream_t stream) {
  const float* x      = (const float*)d_in[0];
  const int*   ei     = (const int*)d_in[1];
  const float* W1     = (const float*)d_in[2];
  const float* a_src1 = (const float*)d_in[3];
  const float* a_dst1 = (const float*)d_in[4];
  const float* b1     = (const float*)d_in[5];
  const float* W2     = (const float*)d_in[6];
  const float* a_src2 = (const float*)d_in[7];
  const float* a_dst2 = (const float*)d_in[8];
  const float* b2     = (const float*)d_in[9];

  int N = in_sizes[0] / 128;
  int E = in_sizes[1] / 2;
  const int* srcI = ei;
  const int* dstI = ei + E;
  int nb = (N + 255) / 256;
  int nWaves = (N + 15) / 16;
  int nSlots1 = nWaves * 2;
  int fillBlocks = (E + 255) / 256;
  int gemm1Blocks = (nSlots1 + 3) / 4;
  int nodeBlocks = (N + 3) / 4;
  int aggBlocks = (N + 15) / 16;

  char* ws = (char*)d_ws;
  size_t o = 0;
  auto alloc = [&](size_t bytes) -> void* {
    void* p = ws + o;
    o += (bytes + 255) & ~(size_t)255;
    return p;
  };
  f16*   h1f    = (f16*)alloc((size_t)N * 256 * 2);
  f16*   h2f    = (f16*)alloc((size_t)N * 64 * 2);
  f16*   Wp1    = (f16*)alloc((size_t)W1_TOT * 2);
  f16*   Wp2    = (f16*)alloc((size_t)W2_TOT * 2);
  float* as1    = (float*)alloc((size_t)N * 8 * 4);
  float* ad1    = (float*)alloc((size_t)N * 8 * 4);
  float* as2    = (float*)alloc((size_t)N * 4);
  float* ad2    = (float*)alloc((size_t)N * 4);
  int*   offs   = (int*)alloc((size_t)(N + 1) * 4);
  int*   deg    = (int*)alloc((size_t)N * 4);
  int*   rank   = (int*)alloc((size_t)E * 4);
  int*   col    = (int*)alloc((size_t)E * 4);
  int*   part   = (int*)alloc((size_t)nb * 4);

  // cooperative CSR front-end (zero+packw | count | scan | offs) in ONE dispatch
  {
    int coopBlocks = 1024;  // 4 blocks/CU x 256 CUs -> guaranteed co-resident
    void* args[] = {
        (void*)&dstI, (void*)&deg, (void*)&rank, (void*)&part, (void*)&offs,
        (void*)&N, (void*)&E, (void*)&nb,
        (void*)&W1, (void*)&a_src1, (void*)&a_dst1,
        (void*)&W2, (void*)&a_src2, (void*)&a_dst2,
        (void*)&Wp1, (void*)&Wp2};
    hipLaunchCooperativeKernel((const void*)k_csr_build, dim3(coopBlocks), dim3(256),
                               args, 0, stream);
  }

  // fused: CSR fill (atomic-free) || Layer-1 GEMM
  k_fill_gemm1<<<fillBlocks + gemm1Blocks, 256, 0, stream>>>(
      srcI, dstI, offs, rank, col, E, fillBlocks,
      x, Wp1, h1f, as1, ad1, N, nSlots1);

  // fused: Layer-1 aggregation + Layer-2 GEMM (r16 stays in LDS)
  k_agg1_gemm2<<<aggBlocks, 256, 0, stream>>>(h1f, as1, ad1, offs, col, b1,
                                              Wp2, h2f, as2, ad2, N);

  // Layer 2 aggregation
  k_agg2<<<nodeBlocks, 256, 0, stream>>>(h2f, as2, ad2, offs, col, b2, (float*)d_out, N);
}

// Round 14
// 205.996 us; speedup vs baseline: 2.7576x; 2.7576x over previous
//
#include <hip/hip_runtime.h>
#include <math.h>

#define NEG_SLOPE 0.2f
__device__ __forceinline__ float leaky(float x) { return fmaxf(x, NEG_SLOPE * x); }

typedef _Float16 f16;
typedef _Float16 f16x4 __attribute__((ext_vector_type(4)));
typedef _Float16 f16x8 __attribute__((ext_vector_type(8)));
typedef float f32x4 __attribute__((ext_vector_type(4)));

__device__ __forceinline__ int kmap(int lh, int e) {
  return (e < 4) ? lh * 4 + e : 16 + lh * 4 + (e - 4);
}

#define W1_TOT (17 * 4 * 64 * 8)
#define W2_TOT (5 * 8 * 64 * 8)

// ---------------- fused: CSR count+rank | weight pack ----------------
__global__ __launch_bounds__(256) void k_count_packw(
    const int* __restrict__ dst, int* __restrict__ deg, int* __restrict__ rank,
    int E, int countBlocks,
    const float* __restrict__ W1, const float* __restrict__ as1f,
    const float* __restrict__ ad1f, const float* __restrict__ W2,
    const float* __restrict__ as2f, const float* __restrict__ ad2f,
    f16* __restrict__ Wp1, f16* __restrict__ Wp2) {
  if ((int)blockIdx.x < countBlocks) {
    int e = blockIdx.x * 256 + threadIdx.x;
    if (e < E) rank[e] = atomicAdd(&deg[dst[e]], 1);
    return;
  }
  int tid = (blockIdx.x - countBlocks) * 256 + threadIdx.x;
  if (tid < W1_TOT) {
    int e = tid & 7, l = (tid >> 3) & 63, ks = (tid >> 9) & 3, nt = tid >> 11;
    int lh = l >> 4, li = l & 15;
    int k = ks * 32 + kmap(lh, e);
    float v;
    if (nt < 16) {
      v = W1[k * 256 + nt * 16 + li];
    } else {
      int h = li & 7;
      const float* a = (li < 8) ? (as1f + h * 32) : (ad1f + h * 32);
      v = 0.f;
      for (int j = 0; j < 32; ++j) v += W1[k * 256 + h * 32 + j] * a[j];
    }
    Wp1[tid] = (f16)v;
  } else if (tid < W1_TOT + W2_TOT) {
    int t2 = tid - W1_TOT;
    int e = t2 & 7, l = (t2 >> 3) & 63, ks = (t2 >> 9) & 7, nt = t2 >> 12;
    int lh = l >> 4, li = l & 15;
    int k = ks * 32 + kmap(lh, e);
    float v = 0.f;
    if (nt < 4) {
      v = W2[k * 64 + nt * 16 + li];
    } else if (li == 0) {
      for (int j = 0; j < 64; ++j) v += W2[k * 64 + j] * as2f[j];
    } else if (li == 1) {
      for (int j = 0; j < 64; ++j) v += W2[k * 64 + j] * ad2f[j];
    }
    Wp2[t2] = (f16)v;
  }
}

// ---------------- single-pass offs: block computes own prefix base + local scan ----------------
__global__ __launch_bounds__(256) void k_offs2(const int* __restrict__ deg,
                                               int* __restrict__ offs, int n) {
  __shared__ int s[256];
  int t = threadIdx.x;
  int c = blockIdx.x;
  // prefix base: sum of deg[0 .. c*256), coalesced grid-stride per block
  int partial = 0;
  int prefixN = c * 256;
  for (int j = t; j < prefixN; j += 256) partial += deg[j];
  s[t] = partial;
  __syncthreads();
  for (int off = 128; off > 0; off >>= 1) {
    if (t < off) s[t] += s[t + off];
    __syncthreads();
  }
  int base = s[0];
  __syncthreads();
  // local exclusive scan of this chunk
  int i = c * 256 + t;
  int v = (i < n) ? deg[i] : 0;
  s[t] = v;
  __syncthreads();
  for (int off = 1; off < 256; off <<= 1) {
    int u = (t >= off) ? s[t - off] : 0;
    __syncthreads();
    s[t] += u;
    __syncthreads();
  }
  int excl = base + s[t] - v;
  if (i < n) offs[i] = excl;
  if (i == n - 1) offs[n] = excl + v;
}

// ---------------- fused: CSR fill (rank-based, no atomics) | MFMA GEMM1 ----------------
__global__ __launch_bounds__(256) void k_fill_gemm1(
    const int* __restrict__ src, const int* __restrict__ dst,
    const int* __restrict__ offs, const int* __restrict__ rank,
    int* __restrict__ col, int E, int fillBlocks,
    const float* __restrict__ x, const f16* __restrict__ Wp1,
    f16* __restrict__ h16, float* __restrict__ as, float* __restrict__ ad,
    int n, int nSlots) {
  if ((int)blockIdx.x < fillBlocks) {
    int e = blockIdx.x * 256 + threadIdx.x;
    if (e >= E) return;
    int d = dst[e];
    col[offs[d] + rank[e]] = src[e];
    return;
  }
  int slot = (blockIdx.x - fillBlocks) * 4 + (threadIdx.x >> 6);
  if (slot >= nSlots) return;
  int half = slot & 1;
  int wid = slot >> 1;
  int lane = threadIdx.x & 63, lh = lane >> 4, li = lane & 15;
  size_t arow = (size_t)min(wid * 16 + li, n - 1);
  f16x8 a[4];
#pragma unroll
  for (int ks = 0; ks < 4; ++ks) {
    float4 lo = *(const float4*)&x[arow * 128 + ks * 32 + lh * 4];
    float4 hi = *(const float4*)&x[arow * 128 + ks * 32 + 16 + lh * 4];
    a[ks][0] = (f16)lo.x; a[ks][1] = (f16)lo.y; a[ks][2] = (f16)lo.z; a[ks][3] = (f16)lo.w;
    a[ks][4] = (f16)hi.x; a[ks][5] = (f16)hi.y; a[ks][6] = (f16)hi.z; a[ks][7] = (f16)hi.w;
  }
  int rbase = wid * 16 + lh * 4;
  int ntBeg = half ? 8 : 0;
  int ntEnd = half ? 17 : 8;
  for (int nt = ntBeg; nt < ntEnd; ++nt) {
    f32x4 acc = {0.f, 0.f, 0.f, 0.f};
#pragma unroll
    for (int ks = 0; ks < 4; ++ks) {
      f16x8 b = *(const f16x8*)&Wp1[((nt * 4 + ks) * 64 + lane) * 8];
      acc = __builtin_amdgcn_mfma_f32_16x16x32_f16(a[ks], b, acc, 0, 0, 0);
    }
    if (nt < 16) {
#pragma unroll
      for (int r = 0; r < 4; ++r) {
        int rr = rbase + r;
        if (rr < n) h16[(size_t)rr * 256 + nt * 16 + li] = (f16)acc[r];
      }
    } else {
#pragma unroll
      for (int r = 0; r < 4; ++r) {
        int rr = rbase + r;
        if (rr < n) {
          if (li < 8) as[(size_t)rr * 8 + li] = acc[r];
          else        ad[(size_t)rr * 8 + (li - 8)] = acc[r];
        }
      }
    }
  }
}

// ---------------- fused: Layer-1 aggregation (16 nodes/block, static) + Layer-2 GEMM from LDS ----------------
#define RPAD 264
__global__ __launch_bounds__(256) void k_agg1_gemm2(const f16* __restrict__ h16,
    const float* __restrict__ as, const float* __restrict__ ad,
    const int* __restrict__ offs, const int* __restrict__ col,
    const float* __restrict__ b, const f16* __restrict__ Wp2,
    f16* __restrict__ h2, float* __restrict__ as2, float* __restrict__ ad2, int n) {
  __shared__ f16 rs[16][RPAD];
  int wave = threadIdx.x >> 6;
  int lane = threadIdx.x & 63;
  int head = lane >> 3;
  int c0 = lane * 4;

  // ---- phase 1: each wave aggregates 4 nodes ----
  for (int i = 0; i < 4; ++i) {
    int rl = wave * 4 + i;
    int node = blockIdx.x * 16 + rl;
    if (node >= n) {
      f16x4 z = {(f16)0.f, (f16)0.f, (f16)0.f, (f16)0.f};
      *(f16x4*)&rs[rl][c0] = z;
      continue;
    }
    node = __builtin_amdgcn_readfirstlane(node);
    int beg = offs[node], end = offs[node + 1];
    float adn = ad[node * 8 + head];

    float denom, ax, ay, az, aw;
    {  // self-loop
      float w = __expf(leaky(as[node * 8 + head] + adn));
      f16x4 g = *(const f16x4*)&h16[(size_t)node * 256 + c0];
      denom = w;
      ax = w * (float)g[0]; ay = w * (float)g[1];
      az = w * (float)g[2]; aw = w * (float)g[3];
    }
    int p = beg;
    for (; p + 8 <= end; p += 8) {
      int s[8];
#pragma unroll
      for (int j = 0; j < 8; ++j) s[j] = col[p + j];
      float e[8];
#pragma unroll
      for (int j = 0; j < 8; ++j) e[j] = as[s[j] * 8 + head];
      f16x4 g[8];
#pragma unroll
      for (int j = 0; j < 8; ++j) g[j] = *(const f16x4*)&h16[(size_t)s[j] * 256 + c0];
      float w[8];
#pragma unroll
      for (int j = 0; j < 8; ++j) w[j] = __expf(leaky(e[j] + adn));
#pragma unroll
      for (int j = 0; j < 8; ++j) {
        denom += w[j];
        ax += w[j] * (float)g[j][0]; ay += w[j] * (float)g[j][1];
        az += w[j] * (float)g[j][2]; aw += w[j] * (float)g[j][3];
      }
    }
    for (; p < end; ++p) {
      int s = col[p];
      float w = __expf(leaky(as[s * 8 + head] + adn));
      f16x4 g = *(const f16x4*)&h16[(size_t)s * 256 + c0];
      denom += w;
      ax += w * (float)g[0]; ay += w * (float)g[1];
      az += w * (float)g[2]; aw += w * (float)g[3];
    }
    float inv = 1.f / denom;
    float4 bv = *(const float4*)&b[c0];
    f16x4 o;
    o[0] = (f16)fmaxf(fmaf(ax, inv, bv.x), 0.f);
    o[1] = (f16)fmaxf(fmaf(ay, inv, bv.y), 0.f);
    o[2] = (f16)fmaxf(fmaf(az, inv, bv.z), 0.f);
    o[3] = (f16)fmaxf(fmaf(aw, inv, bv.w), 0.f);
    *(f16x4*)&rs[rl][c0] = o;
  }
  __syncthreads();

  // ---- phase 2: layer-2 GEMM for these 16 rows (A from LDS) ----
  int lh = lane >> 4, li = lane & 15;
  f16x8 a[8];
#pragma unroll
  for (int ks = 0; ks < 8; ++ks) {
    f16x4 lo = *(const f16x4*)&rs[li][ks * 32 + lh * 4];
    f16x4 hi = *(const f16x4*)&rs[li][ks * 32 + 16 + lh * 4];
    a[ks][0] = lo[0]; a[ks][1] = lo[1]; a[ks][2] = lo[2]; a[ks][3] = lo[3];
    a[ks][4] = hi[0]; a[ks][5] = hi[1]; a[ks][6] = hi[2]; a[ks][7] = hi[3];
  }
  int rbase = blockIdx.x * 16 + lh * 4;
  for (int nt = wave; nt < 5; nt += 4) {
    f32x4 acc = {0.f, 0.f, 0.f, 0.f};
#pragma unroll
    for (int ks = 0; ks < 8; ++ks) {
      f16x8 bb = *(const f16x8*)&Wp2[((nt * 8 + ks) * 64 + lane) * 8];
      acc = __builtin_amdgcn_mfma_f32_16x16x32_f16(a[ks], bb, acc, 0, 0, 0);
    }
    if (nt < 4) {
#pragma unroll
      for (int r = 0; r < 4; ++r) {
        int rr = rbase + r;
        if (rr < n) h2[(size_t)rr * 64 + nt * 16 + li] = (f16)acc[r];
      }
    } else {
#pragma unroll
      for (int r = 0; r < 4; ++r) {
        int rr = rbase + r;
        if (rr < n) {
          if (li == 0) as2[rr] = acc[r];
          else if (li == 1) ad2[rr] = acc[r];
        }
      }
    }
  }
}

// ---------------- Layer 2 aggregation: wave/node, 4 slots x 4 chains ----------------
__global__ __launch_bounds__(256) void k_agg2(const f16* __restrict__ h2,
    const float* __restrict__ as, const float* __restrict__ ad,
    const int* __restrict__ offs, const int* __restrict__ col,
    const float* __restrict__ b, float* __restrict__ out, int n) {
  int node = blockIdx.x * 4 + (threadIdx.x >> 6);
  if (node >= n) return;
  node = __builtin_amdgcn_readfirstlane(node);
  int lane = threadIdx.x & 63;
  int es = lane >> 4;
  int c = lane & 15;
  int beg = offs[node], end = offs[node + 1];
  int deg = end - beg;
  float adn = ad[node];

  float a0 = 0.f, a1 = 0.f, a2 = 0.f, a3 = 0.f, wsum = 0.f;
  if (es == 0) {
    float w = __expf(leaky(as[node] + adn));
    f16x4 g = *(const f16x4*)&h2[(size_t)node * 64 + c * 4];
    wsum = w;
    a0 = w * (float)g[0]; a1 = w * (float)g[1];
    a2 = w * (float)g[2]; a3 = w * (float)g[3];
  }
  for (int base = 0; base < deg; base += 16) {
    int s[4]; float e[4]; f16x4 g[4]; float w[4];
#pragma unroll
    for (int q = 0; q < 4; ++q) {
      int idx = base + q * 4 + es;
      s[q] = (idx < deg) ? col[beg + idx] : node;
    }
#pragma unroll
    for (int q = 0; q < 4; ++q) e[q] = as[s[q]];
#pragma unroll
    for (int q = 0; q < 4; ++q) g[q] = *(const f16x4*)&h2[(size_t)s[q] * 64 + c * 4];
#pragma unroll
    for (int q = 0; q < 4; ++q) {
      int idx = base + q * 4 + es;
      w[q] = (idx < deg) ? __expf(leaky(e[q] + adn)) : 0.f;
    }
#pragma unroll
    for (int q = 0; q < 4; ++q) {
      wsum += w[q];
      a0 += w[q] * (float)g[q][0]; a1 += w[q] * (float)g[q][1];
      a2 += w[q] * (float)g[q][2]; a3 += w[q] * (float)g[q][3];
    }
  }
  a0 += __shfl_xor(a0, 16, 64); a1 += __shfl_xor(a1, 16, 64);
  a2 += __shfl_xor(a2, 16, 64); a3 += __shfl_xor(a3, 16, 64);
  wsum += __shfl_xor(wsum, 16, 64);
  a0 += __shfl_xor(a0, 32, 64); a1 += __shfl_xor(a1, 32, 64);
  a2 += __shfl_xor(a2, 32, 64); a3 += __shfl_xor(a3, 32, 64);
  wsum += __shfl_xor(wsum, 32, 64);
  if (es == 0) {
    float inv = 1.f / wsum;
    float4 bv = *(const float4*)&b[c * 4];
    f32x4 o;
    o[0] = fmaxf(fmaf(a0, inv, bv.x), 0.f);
    o[1] = fmaxf(fmaf(a1, inv, bv.y), 0.f);
    o[2] = fmaxf(fmaf(a2, inv, bv.z), 0.f);
    o[3] = fmaxf(fmaf(a3, inv, bv.w), 0.f);
    __builtin_nontemporal_store(o, (f32x4*)&out[(size_t)node * 64 + c * 4]);
  }
}

extern "C" void kernel_launch(void* const* d_in, const int* in_sizes, int n_in,
                              void* d_out, int out_size, void* d_ws, size_t ws_size,
                              hipStream_t stream) {
  const float* x      = (const float*)d_in[0];
  const int*   ei     = (const int*)d_in[1];
  const float* W1     = (const float*)d_in[2];
  const float* a_src1 = (const float*)d_in[3];
  const float* a_dst1 = (const float*)d_in[4];
  const float* b1     = (const float*)d_in[5];
  const float* W2     = (const float*)d_in[6];
  const float* a_src2 = (const float*)d_in[7];
  const float* a_dst2 = (const float*)d_in[8];
  const float* b2     = (const float*)d_in[9];

  int N = in_sizes[0] / 128;
  int E = in_sizes[1] / 2;
  const int* srcI = ei;
  const int* dstI = ei + E;
  int nb = (N + 255) / 256;
  int nWaves = (N + 15) / 16;
  int nSlots1 = nWaves * 2;
  int countBlocks = (E + 255) / 256;
  int packBlocks = (W1_TOT + W2_TOT + 255) / 256;
  int fillBlocks = (E + 255) / 256;
  int gemm1Blocks = (nSlots1 + 3) / 4;
  int nodeBlocks = (N + 3) / 4;
  int aggBlocks = (N + 15) / 16;

  char* ws = (char*)d_ws;
  size_t o = 0;
  auto alloc = [&](size_t bytes) -> void* {
    void* p = ws + o;
    o += (bytes + 255) & ~(size_t)255;
    return p;
  };
  f16*   h1f    = (f16*)alloc((size_t)N * 256 * 2);
  f16*   h2f    = (f16*)alloc((size_t)N * 64 * 2);
  f16*   Wp1    = (f16*)alloc((size_t)W1_TOT * 2);
  f16*   Wp2    = (f16*)alloc((size_t)W2_TOT * 2);
  float* as1    = (float*)alloc((size_t)N * 8 * 4);
  float* ad1    = (float*)alloc((size_t)N * 8 * 4);
  float* as2    = (float*)alloc((size_t)N * 4);
  float* ad2    = (float*)alloc((size_t)N * 4);
  int*   offs   = (int*)alloc((size_t)(N + 1) * 4);
  int*   deg    = (int*)alloc((size_t)N * 4);
  int*   rank   = (int*)alloc((size_t)E * 4);
  int*   col    = (int*)alloc((size_t)E * 4);

  // CSR front-end: memset -> (count+rank || packw) -> offs (single-pass scan)
  hipMemsetAsync(deg, 0, (size_t)N * 4, stream);
  k_count_packw<<<countBlocks + packBlocks, 256, 0, stream>>>(
      dstI, deg, rank, E, countBlocks,
      W1, a_src1, a_dst1, W2, a_src2, a_dst2, Wp1, Wp2);
  k_offs2<<<nb, 256, 0, stream>>>(deg, offs, N);

  // fused: CSR fill (atomic-free) || Layer-1 GEMM
  k_fill_gemm1<<<fillBlocks + gemm1Blocks, 256, 0, stream>>>(
      srcI, dstI, offs, rank, col, E, fillBlocks,
      x, Wp1, h1f, as1, ad1, N, nSlots1);

  // fused: Layer-1 aggregation + Layer-2 GEMM (r16 stays in LDS)
  k_agg1_gemm2<<<aggBlocks, 256, 0, stream>>>(h1f, as1, ad1, offs, col, b1,
                                              Wp2, h2f, as2, ad2, N);

  // Layer 2 aggregation
  k_agg2<<<nodeBlocks, 256, 0, stream>>>(h2f, as2, ad2, offs, col, b2, (float*)d_out, N);
}

// Round 15
// 184.480 us; speedup vs baseline: 3.0792x; 1.1166x over previous
//
#include <hip/hip_runtime.h>
#include <math.h>

#define NEG_SLOPE 0.2f
__device__ __forceinline__ float leaky(float x) { return fmaxf(x, NEG_SLOPE * x); }

typedef _Float16 f16;
typedef _Float16 f16x4 __attribute__((ext_vector_type(4)));
typedef _Float16 f16x8 __attribute__((ext_vector_type(8)));
typedef float f32x4 __attribute__((ext_vector_type(4)));

__device__ __forceinline__ int kmap(int lh, int e) {
  return (e < 4) ? lh * 4 + e : 16 + lh * 4 + (e - 4);
}

#define W1_TOT (17 * 4 * 64 * 8)
#define W2_TOT (5 * 8 * 64 * 8)

// ---------------- CSR build: count + per-edge rank ----------------
__global__ void k_count(const int* __restrict__ dst, int* __restrict__ deg,
                        int* __restrict__ rank, int E) {
  int e = blockIdx.x * blockDim.x + threadIdx.x;
  if (e < E) {
    int d = dst[e];
    rank[e] = atomicAdd(&deg[d], 1);
  }
}

// ---------------- partial-reduce + weight pack (fused, independent work) ----------------
__global__ __launch_bounds__(256) void k_partial_packw(const int* __restrict__ deg,
    int* __restrict__ part, int n, int nb,
    const float* __restrict__ W1, const float* __restrict__ as1f,
    const float* __restrict__ ad1f, const float* __restrict__ W2,
    const float* __restrict__ as2f, const float* __restrict__ ad2f,
    f16* __restrict__ Wp1, f16* __restrict__ Wp2) {
  if ((int)blockIdx.x < nb) {
    __shared__ int s[256];
    int i = blockIdx.x * 256 + threadIdx.x;
    s[threadIdx.x] = (i < n) ? deg[i] : 0;
    __syncthreads();
    for (int off = 128; off > 0; off >>= 1) {
      if (threadIdx.x < off) s[threadIdx.x] += s[threadIdx.x + off];
      __syncthreads();
    }
    if (threadIdx.x == 0) part[blockIdx.x] = s[0];
  }
  int tid = blockIdx.x * 256 + threadIdx.x;
  if (tid < W1_TOT) {
    int e = tid & 7, l = (tid >> 3) & 63, ks = (tid >> 9) & 3, nt = tid >> 11;
    int lh = l >> 4, li = l & 15;
    int k = ks * 32 + kmap(lh, e);
    float v;
    if (nt < 16) {
      v = W1[k * 256 + nt * 16 + li];
    } else {
      int h = li & 7;
      const float* a = (li < 8) ? (as1f + h * 32) : (ad1f + h * 32);
      v = 0.f;
      for (int j = 0; j < 32; ++j) v += W1[k * 256 + h * 32 + j] * a[j];
    }
    Wp1[tid] = (f16)v;
  } else if (tid < W1_TOT + W2_TOT) {
    int t2 = tid - W1_TOT;
    int e = t2 & 7, l = (t2 >> 3) & 63, ks = (t2 >> 9) & 7, nt = t2 >> 12;
    int lh = l >> 4, li = l & 15;
    int k = ks * 32 + kmap(lh, e);
    float v = 0.f;
    if (nt < 4) {
      v = W2[k * 64 + nt * 16 + li];
    } else if (li == 0) {
      for (int j = 0; j < 64; ++j) v += W2[k * 64 + j] * as2f[j];
    } else if (li == 1) {
      for (int j = 0; j < 64; ++j) v += W2[k * 64 + j] * ad2f[j];
    }
    Wp2[t2] = (f16)v;
  }
}

// scans partials redundantly per block, block-local exclusive scan -> offs.
__global__ __launch_bounds__(256) void k_offs(const int* __restrict__ deg,
                                              const int* __restrict__ part,
                                              int* __restrict__ offs, int n, int nb) {
  __shared__ int ps[256];
  __shared__ int s[256];
  int t = threadIdx.x;
  ps[t] = (t < nb) ? part[t] : 0;
  __syncthreads();
  for (int off = 1; off < 256; off <<= 1) {
    int u = (t >= off) ? ps[t - off] : 0;
    __syncthreads();
    ps[t] += u;
    __syncthreads();
  }
  int base = (blockIdx.x > 0) ? ps[blockIdx.x - 1] : 0;

  int i = blockIdx.x * 256 + t;
  int v = (i < n) ? deg[i] : 0;
  s[t] = v;
  __syncthreads();
  for (int off = 1; off < 256; off <<= 1) {
    int u = (t >= off) ? s[t - off] : 0;
    __syncthreads();
    s[t] += u;
    __syncthreads();
  }
  int excl = base + s[t] - v;
  if (i < n) offs[i] = excl;
  if (i == n - 1) offs[n] = excl + v;
}

// ---------------- fused: CSR fill (rank-based, no atomics) | MFMA GEMM1 ----------------
__global__ __launch_bounds__(256) void k_fill_gemm1(
    const int* __restrict__ src, const int* __restrict__ dst,
    const int* __restrict__ offs, const int* __restrict__ rank,
    int* __restrict__ col, int E, int fillBlocks,
    const float* __restrict__ x, const f16* __restrict__ Wp1,
    f16* __restrict__ h16, float* __restrict__ as, float* __restrict__ ad,
    int n, int nSlots) {
  if ((int)blockIdx.x < fillBlocks) {
    int e = blockIdx.x * 256 + threadIdx.x;
    if (e >= E) return;
    int d = dst[e];
    col[offs[d] + rank[e]] = src[e];
    return;
  }
  int slot = (blockIdx.x - fillBlocks) * 4 + (threadIdx.x >> 6);
  if (slot >= nSlots) return;
  int half = slot & 1;
  int wid = slot >> 1;
  int lane = threadIdx.x & 63, lh = lane >> 4, li = lane & 15;
  size_t arow = (size_t)min(wid * 16 + li, n - 1);
  f16x8 a[4];
#pragma unroll
  for (int ks = 0; ks < 4; ++ks) {
    float4 lo = *(const float4*)&x[arow * 128 + ks * 32 + lh * 4];
    float4 hi = *(const float4*)&x[arow * 128 + ks * 32 + 16 + lh * 4];
    a[ks][0] = (f16)lo.x; a[ks][1] = (f16)lo.y; a[ks][2] = (f16)lo.z; a[ks][3] = (f16)lo.w;
    a[ks][4] = (f16)hi.x; a[ks][5] = (f16)hi.y; a[ks][6] = (f16)hi.z; a[ks][7] = (f16)hi.w;
  }
  int rbase = wid * 16 + lh * 4;
  int ntBeg = half ? 8 : 0;
  int ntEnd = half ? 17 : 8;
  for (int nt = ntBeg; nt < ntEnd; ++nt) {
    f32x4 acc = {0.f, 0.f, 0.f, 0.f};
#pragma unroll
    for (int ks = 0; ks < 4; ++ks) {
      f16x8 b = *(const f16x8*)&Wp1[((nt * 4 + ks) * 64 + lane) * 8];
      acc = __builtin_amdgcn_mfma_f32_16x16x32_f16(a[ks], b, acc, 0, 0, 0);
    }
    if (nt < 16) {
#pragma unroll
      for (int r = 0; r < 4; ++r) {
        int rr = rbase + r;
        if (rr < n) h16[(size_t)rr * 256 + nt * 16 + li] = (f16)acc[r];
      }
    } else {
#pragma unroll
      for (int r = 0; r < 4; ++r) {
        int rr = rbase + r;
        if (rr < n) {
          if (li < 8) as[(size_t)rr * 8 + li] = acc[r];
          else        ad[(size_t)rr * 8 + (li - 8)] = acc[r];
        }
      }
    }
  }
}

// ---------------- fused: Layer-1 aggregation (16 nodes/block, static) + Layer-2 GEMM from LDS ----------------
#define RPAD 264
__global__ __launch_bounds__(256) void k_agg1_gemm2(const f16* __restrict__ h16,
    const float* __restrict__ as, const float* __restrict__ ad,
    const int* __restrict__ offs, const int* __restrict__ col,
    const float* __restrict__ b, const f16* __restrict__ Wp2,
    f16* __restrict__ h2, float* __restrict__ as2, float* __restrict__ ad2, int n) {
  __shared__ f16 rs[16][RPAD];
  int wave = threadIdx.x >> 6;
  int lane = threadIdx.x & 63;
  int head = lane >> 3;
  int c0 = lane * 4;

  // ---- phase 1: each wave aggregates 4 nodes ----
  for (int i = 0; i < 4; ++i) {
    int rl = wave * 4 + i;
    int node = blockIdx.x * 16 + rl;
    if (node >= n) {
      f16x4 z = {(f16)0.f, (f16)0.f, (f16)0.f, (f16)0.f};
      *(f16x4*)&rs[rl][c0] = z;
      continue;
    }
    node = __builtin_amdgcn_readfirstlane(node);
    int beg = offs[node], end = offs[node + 1];
    float adn = ad[node * 8 + head];

    float denom, ax, ay, az, aw;
    {  // self-loop
      float w = __expf(leaky(as[node * 8 + head] + adn));
      f16x4 g = *(const f16x4*)&h16[(size_t)node * 256 + c0];
      denom = w;
      ax = w * (float)g[0]; ay = w * (float)g[1];
      az = w * (float)g[2]; aw = w * (float)g[3];
    }
    int p = beg;
    for (; p + 8 <= end; p += 8) {
      int s[8];
#pragma unroll
      for (int j = 0; j < 8; ++j) s[j] = col[p + j];
      float e[8];
#pragma unroll
      for (int j = 0; j < 8; ++j) e[j] = as[s[j] * 8 + head];
      f16x4 g[8];
#pragma unroll
      for (int j = 0; j < 8; ++j) g[j] = *(const f16x4*)&h16[(size_t)s[j] * 256 + c0];
      float w[8];
#pragma unroll
      for (int j = 0; j < 8; ++j) w[j] = __expf(leaky(e[j] + adn));
#pragma unroll
      for (int j = 0; j < 8; ++j) {
        denom += w[j];
        ax += w[j] * (float)g[j][0]; ay += w[j] * (float)g[j][1];
        az += w[j] * (float)g[j][2]; aw += w[j] * (float)g[j][3];
      }
    }
    for (; p < end; ++p) {
      int s = col[p];
      float w = __expf(leaky(as[s * 8 + head] + adn));
      f16x4 g = *(const f16x4*)&h16[(size_t)s * 256 + c0];
      denom += w;
      ax += w * (float)g[0]; ay += w * (float)g[1];
      az += w * (float)g[2]; aw += w * (float)g[3];
    }
    float inv = 1.f / denom;
    float4 bv = *(const float4*)&b[c0];
    f16x4 o;
    o[0] = (f16)fmaxf(fmaf(ax, inv, bv.x), 0.f);
    o[1] = (f16)fmaxf(fmaf(ay, inv, bv.y), 0.f);
    o[2] = (f16)fmaxf(fmaf(az, inv, bv.z), 0.f);
    o[3] = (f16)fmaxf(fmaf(aw, inv, bv.w), 0.f);
    *(f16x4*)&rs[rl][c0] = o;
  }
  __syncthreads();

  // ---- phase 2: layer-2 GEMM for these 16 rows (A from LDS) ----
  int lh = lane >> 4, li = lane & 15;
  f16x8 a[8];
#pragma unroll
  for (int ks = 0; ks < 8; ++ks) {
    f16x4 lo = *(const f16x4*)&rs[li][ks * 32 + lh * 4];
    f16x4 hi = *(const f16x4*)&rs[li][ks * 32 + 16 + lh * 4];
    a[ks][0] = lo[0]; a[ks][1] = lo[1]; a[ks][2] = lo[2]; a[ks][3] = lo[3];
    a[ks][4] = hi[0]; a[ks][5] = hi[1]; a[ks][6] = hi[2]; a[ks][7] = hi[3];
  }
  int rbase = blockIdx.x * 16 + lh * 4;
  for (int nt = wave; nt < 5; nt += 4) {
    f32x4 acc = {0.f, 0.f, 0.f, 0.f};
#pragma unroll
    for (int ks = 0; ks < 8; ++ks) {
      f16x8 bb = *(const f16x8*)&Wp2[((nt * 8 + ks) * 64 + lane) * 8];
      acc = __builtin_amdgcn_mfma_f32_16x16x32_f16(a[ks], bb, acc, 0, 0, 0);
    }
    if (nt < 4) {
#pragma unroll
      for (int r = 0; r < 4; ++r) {
        int rr = rbase + r;
        if (rr < n) h2[(size_t)rr * 64 + nt * 16 + li] = (f16)acc[r];
      }
    } else {
#pragma unroll
      for (int r = 0; r < 4; ++r) {
        int rr = rbase + r;
        if (rr < n) {
          if (li == 0) as2[rr] = acc[r];
          else if (li == 1) ad2[rr] = acc[r];
        }
      }
    }
  }
}

// ---------------- Layer 2 aggregation: wave/node, 4 slots x 4 chains ----------------
__global__ __launch_bounds__(256) void k_agg2(const f16* __restrict__ h2,
    const float* __restrict__ as, const float* __restrict__ ad,
    const int* __restrict__ offs, const int* __restrict__ col,
    const float* __restrict__ b, float* __restrict__ out, int n) {
  int node = blockIdx.x * 4 + (threadIdx.x >> 6);
  if (node >= n) return;
  node = __builtin_amdgcn_readfirstlane(node);
  int lane = threadIdx.x & 63;
  int es = lane >> 4;
  int c = lane & 15;
  int beg = offs[node], end = offs[node + 1];
  int deg = end - beg;
  float adn = ad[node];

  float a0 = 0.f, a1 = 0.f, a2 = 0.f, a3 = 0.f, wsum = 0.f;
  if (es == 0) {
    float w = __expf(leaky(as[node] + adn));
    f16x4 g = *(const f16x4*)&h2[(size_t)node * 64 + c * 4];
    wsum = w;
    a0 = w * (float)g[0]; a1 = w * (float)g[1];
    a2 = w * (float)g[2]; a3 = w * (float)g[3];
  }
  for (int base = 0; base < deg; base += 16) {
    int s[4]; float e[4]; f16x4 g[4]; float w[4];
#pragma unroll
    for (int q = 0; q < 4; ++q) {
      int idx = base + q * 4 + es;
      s[q] = (idx < deg) ? col[beg + idx] : node;
    }
#pragma unroll
    for (int q = 0; q < 4; ++q) e[q] = as[s[q]];
#pragma unroll
    for (int q = 0; q < 4; ++q) g[q] = *(const f16x4*)&h2[(size_t)s[q] * 64 + c * 4];
#pragma unroll
    for (int q = 0; q < 4; ++q) {
      int idx = base + q * 4 + es;
      w[q] = (idx < deg) ? __expf(leaky(e[q] + adn)) : 0.f;
    }
#pragma unroll
    for (int q = 0; q < 4; ++q) {
      wsum += w[q];
      a0 += w[q] * (float)g[q][0]; a1 += w[q] * (float)g[q][1];
      a2 += w[q] * (float)g[q][2]; a3 += w[q] * (float)g[q][3];
    }
  }
  a0 += __shfl_xor(a0, 16, 64); a1 += __shfl_xor(a1, 16, 64);
  a2 += __shfl_xor(a2, 16, 64); a3 += __shfl_xor(a3, 16, 64);
  wsum += __shfl_xor(wsum, 16, 64);
  a0 += __shfl_xor(a0, 32, 64); a1 += __shfl_xor(a1, 32, 64);
  a2 += __shfl_xor(a2, 32, 64); a3 += __shfl_xor(a3, 32, 64);
  wsum += __shfl_xor(wsum, 32, 64);
  if (es == 0) {
    float inv = 1.f / wsum;
    float4 bv = *(const float4*)&b[c * 4];
    f32x4 o;
    o[0] = fmaxf(fmaf(a0, inv, bv.x), 0.f);
    o[1] = fmaxf(fmaf(a1, inv, bv.y), 0.f);
    o[2] = fmaxf(fmaf(a2, inv, bv.z), 0.f);
    o[3] = fmaxf(fmaf(a3, inv, bv.w), 0.f);
    __builtin_nontemporal_store(o, (f32x4*)&out[(size_t)node * 64 + c * 4]);
  }
}

extern "C" void kernel_launch(void* const* d_in, const int* in_sizes, int n_in,
                              void* d_out, int out_size, void* d_ws, size_t ws_size,
                              hipStream_t stream) {
  const float* x      = (const float*)d_in[0];
  const int*   ei     = (const int*)d_in[1];
  const float* W1     = (const float*)d_in[2];
  const float* a_src1 = (const float*)d_in[3];
  const float* a_dst1 = (const float*)d_in[4];
  const float* b1     = (const float*)d_in[5];
  const float* W2     = (const float*)d_in[6];
  const float* a_src2 = (const float*)d_in[7];
  const float* a_dst2 = (const float*)d_in[8];
  const float* b2     = (const float*)d_in[9];

  int N = in_sizes[0] / 128;
  int E = in_sizes[1] / 2;
  const int* srcI = ei;
  const int* dstI = ei + E;
  int nb = (N + 255) / 256;
  int packBlocks = (W1_TOT + W2_TOT + 255) / 256;
  int ppBlocks = nb > packBlocks ? nb : packBlocks;
  int nWaves = (N + 15) / 16;
  int nSlots1 = nWaves * 2;
  int fillBlocks = (E + 255) / 256;
  int gemm1Blocks = (nSlots1 + 3) / 4;
  int nodeBlocks = (N + 3) / 4;
  int aggBlocks = (N + 15) / 16;

  char* ws = (char*)d_ws;
  size_t o = 0;
  auto alloc = [&](size_t bytes) -> void* {
    void* p = ws + o;
    o += (bytes + 255) & ~(size_t)255;
    return p;
  };
  f16*   h1f    = (f16*)alloc((size_t)N * 256 * 2);
  f16*   h2f    = (f16*)alloc((size_t)N * 64 * 2);
  f16*   Wp1    = (f16*)alloc((size_t)W1_TOT * 2);
  f16*   Wp2    = (f16*)alloc((size_t)W2_TOT * 2);
  float* as1    = (float*)alloc((size_t)N * 8 * 4);
  float* ad1    = (float*)alloc((size_t)N * 8 * 4);
  float* as2    = (float*)alloc((size_t)N * 4);
  float* ad2    = (float*)alloc((size_t)N * 4);
  int*   offs   = (int*)alloc((size_t)(N + 1) * 4);
  int*   deg    = (int*)alloc((size_t)N * 4);
  int*   rank   = (int*)alloc((size_t)E * 4);
  int*   col    = (int*)alloc((size_t)E * 4);
  int*   part   = (int*)alloc((size_t)nb * 4);

  // CSR front-end (R12-proven): memset -> count+rank -> (partial || packw) -> offs
  hipMemsetAsync(deg, 0, (size_t)N * 4, stream);
  k_count<<<(E + 255) / 256, 256, 0, stream>>>(dstI, deg, rank, E);
  k_partial_packw<<<ppBlocks, 256, 0, stream>>>(deg, part, N, nb,
      W1, a_src1, a_dst1, W2, a_src2, a_dst2, Wp1, Wp2);
  k_offs<<<nb, 256, 0, stream>>>(deg, part, offs, N, nb);

  // fused: CSR fill (atomic-free) || Layer-1 GEMM
  k_fill_gemm1<<<fillBlocks + gemm1Blocks, 256, 0, stream>>>(
      srcI, dstI, offs, rank, col, E, fillBlocks,
      x, Wp1, h1f, as1, ad1, N, nSlots1);

  // fused: Layer-1 aggregation (static) + Layer-2 GEMM (r16 stays in LDS)
  k_agg1_gemm2<<<aggBlocks, 256, 0, stream>>>(h1f, as1, ad1, offs, col, b1,
                                              Wp2, h2f, as2, ad2, N);

  // Layer 2 aggregation
  k_agg2<<<nodeBlocks, 256, 0, stream>>>(h2f, as2, ad2, offs, col, b2, (float*)d_out, N);
}